// Round 5
// baseline (239.792 us; speedup 1.0000x reference)
//
#include <hip/hip_runtime.h>

#define NPTS 16384
#define PW 16
#define NU (1.0f / 100.0f)

typedef _Float16 f16;
typedef __attribute__((ext_vector_type(8))) _Float16 f16x8;
typedef __attribute__((ext_vector_type(4))) float f32x4;

// granule swizzle within a 64-granule (16B each) tile: bijective, same on
// write and read; spreads activation writes over all bank groups.
__device__ __forceinline__ int swz(int g) { return g ^ ((g >> 3) & 7); }

// ---- prep: W1..W5 (256x256) and W6 (256x3 zero-padded to 16 cols) -> MFMA
// B-fragment order, single f16 plane.
// B-frag (16x16x32): lane l holds B[k = kc*32 + 8*(l>>4) + j][n = nf*16 + (l&15)], j=0..7.
__global__ __launch_bounds__(256) void prep_kernel(
    const float* __restrict__ W1, const float* __restrict__ W2,
    const float* __restrict__ W3, const float* __restrict__ W4,
    const float* __restrict__ W5, const float* __restrict__ W6,
    f16* __restrict__ bh, f16* __restrict__ b6h)
{
    int idx = blockIdx.x * 256 + threadIdx.x;
    if (idx < 40960) {
        int col = idx & 255, subk = (idx >> 8) & 3, kc = (idx >> 10) & 7, L = idx >> 13;
        const float* W = (L == 0) ? W1 : (L == 1) ? W2 : (L == 2) ? W3 : (L == 3) ? W4 : W5;
        f16x8 vh;
        #pragma unroll
        for (int j = 0; j < 8; ++j) {
            int k = kc * 32 + subk * 8 + j;
            vh[j] = (f16)W[k * 256 + col];
        }
        int nf = col >> 4, l15 = col & 15, lane = subk * 16 + l15;
        *(f16x8*)(bh + (((L * 8 + kc) * 16 + nf) * 64 + lane) * 8) = vh;
    } else {
        int u = idx - 40960;
        if (u < 512) {
            int col = u & 15, subk = (u >> 4) & 3, kc = u >> 6;
            f16x8 vh;
            #pragma unroll
            for (int j = 0; j < 8; ++j) {
                int k = kc * 32 + subk * 8 + j;
                vh[j] = (f16)((col < 3) ? W6[k * 3 + col] : 0.f);
            }
            *(f16x8*)(b6h + (kc * 64 + subk * 16 + col) * 8) = vh;
        }
    }
}

// ---- main: PW=16 points/block, 4 waves (256 thr), 3 blocks/CU.
// State rows = c*16+p (c: 0=val,1=dt,2=dx,3=dy,4=dxx,5=dyy).
// A tile (c,kc): 64 granules of 16B; granule g holds
// A[row = g&15][k = kc*32 + 8*(g>>4) + 0..7], stored at swz(g).
// Wave nq owns cols [nq*64, nq*64+64) (4 n-frags).
__global__ __launch_bounds__(256, 3) void pinn_ns_mfma(
    const float* __restrict__ t_, const float* __restrict__ x_, const float* __restrict__ y_,
    const float* __restrict__ W0, const float* __restrict__ b0,
    const float* __restrict__ b1, const float* __restrict__ b2,
    const float* __restrict__ b3, const float* __restrict__ b4,
    const float* __restrict__ b5, const float* __restrict__ b6,
    const f16* __restrict__ bh, const f16* __restrict__ b6h,
    float* __restrict__ out)
{
    __shared__ __align__(16) f16 afrag[6 * 8 * 512];   // 49152 B
    __shared__ float z6buf[6 * 16 * 4];

    const int tid = threadIdx.x;
    const int lane = tid & 63;
    const int nq = tid >> 6;           // wave = n-quad: cols nq*64 .. +63
    const int gl = swz(lane);          // A-read granule
    const int p0 = blockIdx.x * PW;

    // ---- layer 0: 3 -> 256 elementwise
    {
        int j = tid;
        float wt = W0[j], wx = W0[256 + j], wy = W0[512 + j], bb0 = b0[j];
        int kc = j >> 5, sub = (j >> 3) & 3, jj = j & 7;
        #pragma unroll
        for (int p = 0; p < PW; ++p) {
            float tv = t_[p0 + p], xv = x_[p0 + p], yv = y_[p0 + p];
            float z = tv * wt + xv * wx + yv * wy + bb0;
            float sv, cv;
            __sincosf(z, &sv, &cv);
            float nv[6] = {sv, cv * wt, cv * wx, cv * wy, -sv * wx * wx, -sv * wy * wy};
            int g = swz(sub * 16 + p);
            #pragma unroll
            for (int c = 0; c < 6; ++c)
                afrag[((c * 8 + kc) * 64 + g) * 8 + jj] = (f16)nv[c];
        }
    }
    __syncthreads();

    // ---- layers 1..5
    const float* bias[5] = {b1, b2, b3, b4, b5};
    const f16x8* A = (const f16x8*)afrag;
    for (int L = 0; L < 5; ++L) {
        const f16x8* bH = (const f16x8*)bh + L * 8192;
        f32x4 acc[6][4];
        #pragma unroll
        for (int c = 0; c < 6; ++c)
            #pragma unroll
            for (int f = 0; f < 4; ++f)
                acc[c][f] = (f32x4){0.f, 0.f, 0.f, 0.f};

        f16x8 Bc[4];
        #pragma unroll
        for (int f = 0; f < 4; ++f)
            Bc[f] = bH[(nq * 4 + f) * 64 + lane];

        #pragma unroll
        for (int kc = 0; kc < 8; ++kc) {
            f16x8 Bn[4];
            if (kc < 7) {
                #pragma unroll
                for (int f = 0; f < 4; ++f)
                    Bn[f] = bH[((kc + 1) * 16 + nq * 4 + f) * 64 + lane];
            }
            #pragma unroll
            for (int c = 0; c < 6; ++c) {
                f16x8 Ah = A[(c * 8 + kc) * 64 + gl];
                #pragma unroll
                for (int f = 0; f < 4; ++f)
                    acc[c][f] = __builtin_amdgcn_mfma_f32_16x16x32_f16(Ah, Bc[f], acc[c][f], 0, 0, 0);
            }
            if (kc < 7) {
                #pragma unroll
                for (int f = 0; f < 4; ++f)
                    Bc[f] = Bn[f];
            }
        }
        __syncthreads();  // all A-reads done before overwrite

        const float* bbp = bias[L];
        #pragma unroll
        for (int f = 0; f < 4; ++f) {
            int col = nq * 64 + f * 16 + (lane & 15);
            int kcw = col >> 5;
            int sub = (col >> 3) & 3, jj = col & 7;
            float bvf = bbp[col];
            #pragma unroll
            for (int r = 0; r < 4; ++r) {
                int rw = (lane >> 4) * 4 + r;
                float z = acc[0][f][r] + bvf;
                float zt = acc[1][f][r], zx = acc[2][f][r], zy = acc[3][f][r];
                float zxx = acc[4][f][r], zyy = acc[5][f][r];
                float sv, cv;
                __sincosf(z, &sv, &cv);
                float nv[6] = {sv, cv * zt, cv * zx, cv * zy,
                               cv * zxx - sv * zx * zx, cv * zyy - sv * zy * zy};
                int g = swz(sub * 16 + rw);
                #pragma unroll
                for (int c = 0; c < 6; ++c)
                    afrag[((c * 8 + kcw) * 64 + g) * 8 + jj] = (f16)nv[c];
            }
        }
        __syncthreads();
    }

    // ---- layer 6: 256 -> 3 (cols 3..15 zero). Wave wv handles channels wv, wv+4.
    for (int cc = nq; cc < 6; cc += 4) {
        f32x4 a6 = {0.f, 0.f, 0.f, 0.f};
        const f16x8* b6H = (const f16x8*)b6h;
        #pragma unroll
        for (int kc = 0; kc < 8; ++kc) {
            f16x8 Ah = A[(cc * 8 + kc) * 64 + gl];
            a6 = __builtin_amdgcn_mfma_f32_16x16x32_f16(Ah, b6H[kc * 64 + lane], a6, 0, 0, 0);
        }
        int col = lane & 15;
        if (col < 3) {
            float badd = (cc == 0) ? b6[col] : 0.f;
            #pragma unroll
            for (int r = 0; r < 4; ++r)
                z6buf[(cc * 16 + (lane >> 4) * 4 + r) * 4 + col] = a6[r] + badd;
        }
    }
    __syncthreads();

    // ---- residuals
    if (tid < PW) {
        int p = tid, g = p0 + p;
        float u_  = z6buf[(0  + p) * 4 + 0], v_  = z6buf[(0  + p) * 4 + 1];
        float ut  = z6buf[(16 + p) * 4 + 0], vt  = z6buf[(16 + p) * 4 + 1];
        float ux  = z6buf[(32 + p) * 4 + 0], vx  = z6buf[(32 + p) * 4 + 1], px = z6buf[(32 + p) * 4 + 2];
        float uy  = z6buf[(48 + p) * 4 + 0], vy  = z6buf[(48 + p) * 4 + 1], py = z6buf[(48 + p) * 4 + 2];
        float uxx = z6buf[(64 + p) * 4 + 0], vxx = z6buf[(64 + p) * 4 + 1];
        float uyy = z6buf[(80 + p) * 4 + 0], vyy = z6buf[(80 + p) * 4 + 1];
        out[g]            = ut + (u_ * ux + v_ * uy) + px - NU * (uxx + uyy);
        out[NPTS + g]     = vt + (u_ * vx + v_ * vy) + py - NU * (vxx + vyy);
        out[2 * NPTS + g] = ux + vy;
    }
}

extern "C" void kernel_launch(void* const* d_in, const int* in_sizes, int n_in,
                              void* d_out, int out_size, void* d_ws, size_t ws_size,
                              hipStream_t stream) {
    const float* t_ = (const float*)d_in[0];
    const float* x_ = (const float*)d_in[1];
    const float* y_ = (const float*)d_in[2];
    const float* W[7];
    const float* b[7];
    for (int i = 0; i < 7; ++i) {
        W[i] = (const float*)d_in[3 + 2 * i];
        b[i] = (const float*)d_in[4 + 2 * i];
    }
    float* out = (float*)d_out;

    f16* bh  = (f16*)d_ws;               // 327680 f16
    f16* b6h = bh + 5 * 65536;           // 4096 f16

    hipLaunchKernelGGL(prep_kernel, dim3(162), dim3(256), 0, stream,
                       W[1], W[2], W[3], W[4], W[5], W[6], bh, b6h);
    hipLaunchKernelGGL(pinn_ns_mfma, dim3(NPTS / PW), dim3(256), 0, stream,
                       t_, x_, y_, W[0], b[0],
                       b[1], b[2], b[3], b[4], b[5], b[6],
                       bh, b6h, out);
}

// Round 6
// 151.627 us; speedup vs baseline: 1.5815x; 1.5815x over previous
//
#include <hip/hip_runtime.h>

#define NPTS 16384
#define PW 16
#define NU (1.0f / 100.0f)

typedef _Float16 f16;
typedef __attribute__((ext_vector_type(8))) _Float16 f16x8;
typedef __attribute__((ext_vector_type(4))) float f32x4;

// granule swizzle within a 64-granule (16B each) tile: bijective, same on
// write and read; spreads activation writes over all bank groups.
__device__ __forceinline__ int swz(int g) { return g ^ ((g >> 3) & 7); }

// ---- prep: W1..W5 (256x256) and W6 (256x3 zero-padded to 16 cols) -> MFMA
// B-fragment order, single f16 plane.
// B-frag (16x16x32): lane l holds B[k = kc*32 + 8*(l>>4) + j][n = nf*16 + (l&15)], j=0..7.
__global__ __launch_bounds__(256) void prep_kernel(
    const float* __restrict__ W1, const float* __restrict__ W2,
    const float* __restrict__ W3, const float* __restrict__ W4,
    const float* __restrict__ W5, const float* __restrict__ W6,
    f16* __restrict__ bh, f16* __restrict__ b6h)
{
    int idx = blockIdx.x * 256 + threadIdx.x;
    if (idx < 40960) {
        int col = idx & 255, subk = (idx >> 8) & 3, kc = (idx >> 10) & 7, L = idx >> 13;
        const float* W = (L == 0) ? W1 : (L == 1) ? W2 : (L == 2) ? W3 : (L == 3) ? W4 : W5;
        f16x8 vh;
        #pragma unroll
        for (int j = 0; j < 8; ++j) {
            int k = kc * 32 + subk * 8 + j;
            vh[j] = (f16)W[k * 256 + col];
        }
        int nf = col >> 4, l15 = col & 15, lane = subk * 16 + l15;
        *(f16x8*)(bh + (((L * 8 + kc) * 16 + nf) * 64 + lane) * 8) = vh;
    } else {
        int u = idx - 40960;
        if (u < 512) {
            int col = u & 15, subk = (u >> 4) & 3, kc = u >> 6;
            f16x8 vh;
            #pragma unroll
            for (int j = 0; j < 8; ++j) {
                int k = kc * 32 + subk * 8 + j;
                vh[j] = (f16)((col < 3) ? W6[k * 3 + col] : 0.f);
            }
            *(f16x8*)(b6h + (kc * 64 + subk * 16 + col) * 8) = vh;
        }
    }
}

// ---- main: PW=16 points/block, 4 waves (256 thr), target 2+ blocks/CU.
// State rows = c*16+p (c: 0=val,1=dt,2=dx,3=dy,4=dxx,5=dyy).
// A tile (c,kc): 64 granules of 16B; granule g holds
// A[row = g&15][k = kc*32 + 8*(g>>4) + 0..7], stored at swz(g).
// Wave nq owns cols [nq*64, nq*64+64) (4 n-frags).
// NOTE: plain __launch_bounds__(256). (256,3) made the allocator split the
// unified RF ~84/84 and spill the 96-reg accumulator tile -> 190 MB/dispatch
// scratch traffic (round-5 regression).
__global__ __launch_bounds__(256) void pinn_ns_mfma(
    const float* __restrict__ t_, const float* __restrict__ x_, const float* __restrict__ y_,
    const float* __restrict__ W0, const float* __restrict__ b0,
    const float* __restrict__ b1, const float* __restrict__ b2,
    const float* __restrict__ b3, const float* __restrict__ b4,
    const float* __restrict__ b5, const float* __restrict__ b6,
    const f16* __restrict__ bh, const f16* __restrict__ b6h,
    float* __restrict__ out)
{
    __shared__ __align__(16) f16 afrag[6 * 8 * 512];   // 49152 B
    __shared__ float z6buf[6 * 16 * 4];

    const int tid = threadIdx.x;
    const int lane = tid & 63;
    const int nq = tid >> 6;           // wave = n-quad: cols nq*64 .. +63
    const int gl = swz(lane);          // A-read granule
    const int p0 = blockIdx.x * PW;

    // ---- layer 0: 3 -> 256 elementwise
    {
        int j = tid;
        float wt = W0[j], wx = W0[256 + j], wy = W0[512 + j], bb0 = b0[j];
        int kc = j >> 5, sub = (j >> 3) & 3, jj = j & 7;
        #pragma unroll
        for (int p = 0; p < PW; ++p) {
            float tv = t_[p0 + p], xv = x_[p0 + p], yv = y_[p0 + p];
            float z = tv * wt + xv * wx + yv * wy + bb0;
            float sv, cv;
            __sincosf(z, &sv, &cv);
            float nv[6] = {sv, cv * wt, cv * wx, cv * wy, -sv * wx * wx, -sv * wy * wy};
            int g = swz(sub * 16 + p);
            #pragma unroll
            for (int c = 0; c < 6; ++c)
                afrag[((c * 8 + kc) * 64 + g) * 8 + jj] = (f16)nv[c];
        }
    }
    __syncthreads();

    // ---- layers 1..5
    const float* bias[5] = {b1, b2, b3, b4, b5};
    const f16x8* A = (const f16x8*)afrag;
    for (int L = 0; L < 5; ++L) {
        const f16x8* bH = (const f16x8*)bh + L * 8192;
        f32x4 acc[6][4];
        #pragma unroll
        for (int c = 0; c < 6; ++c)
            #pragma unroll
            for (int f = 0; f < 4; ++f)
                acc[c][f] = (f32x4){0.f, 0.f, 0.f, 0.f};

        f16x8 Bc[4];
        #pragma unroll
        for (int f = 0; f < 4; ++f)
            Bc[f] = bH[(nq * 4 + f) * 64 + lane];

        #pragma unroll
        for (int kc = 0; kc < 8; ++kc) {
            f16x8 Bn[4];
            if (kc < 7) {
                #pragma unroll
                for (int f = 0; f < 4; ++f)
                    Bn[f] = bH[((kc + 1) * 16 + nq * 4 + f) * 64 + lane];
            }
            #pragma unroll
            for (int c = 0; c < 6; ++c) {
                f16x8 Ah = A[(c * 8 + kc) * 64 + gl];
                #pragma unroll
                for (int f = 0; f < 4; ++f)
                    acc[c][f] = __builtin_amdgcn_mfma_f32_16x16x32_f16(Ah, Bc[f], acc[c][f], 0, 0, 0);
            }
            if (kc < 7) {
                #pragma unroll
                for (int f = 0; f < 4; ++f)
                    Bc[f] = Bn[f];
            }
        }
        __syncthreads();  // all A-reads done before overwrite

        const float* bbp = bias[L];
        #pragma unroll
        for (int f = 0; f < 4; ++f) {
            int col = nq * 64 + f * 16 + (lane & 15);
            int kcw = col >> 5;
            int sub = (col >> 3) & 3, jj = col & 7;
            float bvf = bbp[col];
            #pragma unroll
            for (int r = 0; r < 4; ++r) {
                int rw = (lane >> 4) * 4 + r;
                float z = acc[0][f][r] + bvf;
                float zt = acc[1][f][r], zx = acc[2][f][r], zy = acc[3][f][r];
                float zxx = acc[4][f][r], zyy = acc[5][f][r];
                float sv, cv;
                __sincosf(z, &sv, &cv);
                float nv[6] = {sv, cv * zt, cv * zx, cv * zy,
                               cv * zxx - sv * zx * zx, cv * zyy - sv * zy * zy};
                int g = swz(sub * 16 + rw);
                #pragma unroll
                for (int c = 0; c < 6; ++c)
                    afrag[((c * 8 + kcw) * 64 + g) * 8 + jj] = (f16)nv[c];
            }
        }
        __syncthreads();
    }

    // ---- layer 6: 256 -> 3 (cols 3..15 zero). Wave nq handles channels nq, nq+4.
    for (int cc = nq; cc < 6; cc += 4) {
        f32x4 a6 = {0.f, 0.f, 0.f, 0.f};
        const f16x8* b6H = (const f16x8*)b6h;
        #pragma unroll
        for (int kc = 0; kc < 8; ++kc) {
            f16x8 Ah = A[(cc * 8 + kc) * 64 + gl];
            a6 = __builtin_amdgcn_mfma_f32_16x16x32_f16(Ah, b6H[kc * 64 + lane], a6, 0, 0, 0);
        }
        int col = lane & 15;
        if (col < 3) {
            float badd = (cc == 0) ? b6[col] : 0.f;
            #pragma unroll
            for (int r = 0; r < 4; ++r)
                z6buf[(cc * 16 + (lane >> 4) * 4 + r) * 4 + col] = a6[r] + badd;
        }
    }
    __syncthreads();

    // ---- residuals
    if (tid < PW) {
        int p = tid, g = p0 + p;
        float u_  = z6buf[(0  + p) * 4 + 0], v_  = z6buf[(0  + p) * 4 + 1];
        float ut  = z6buf[(16 + p) * 4 + 0], vt  = z6buf[(16 + p) * 4 + 1];
        float ux  = z6buf[(32 + p) * 4 + 0], vx  = z6buf[(32 + p) * 4 + 1], px = z6buf[(32 + p) * 4 + 2];
        float uy  = z6buf[(48 + p) * 4 + 0], vy  = z6buf[(48 + p) * 4 + 1], py = z6buf[(48 + p) * 4 + 2];
        float uxx = z6buf[(64 + p) * 4 + 0], vxx = z6buf[(64 + p) * 4 + 1];
        float uyy = z6buf[(80 + p) * 4 + 0], vyy = z6buf[(80 + p) * 4 + 1];
        out[g]            = ut + (u_ * ux + v_ * uy) + px - NU * (uxx + uyy);
        out[NPTS + g]     = vt + (u_ * vx + v_ * vy) + py - NU * (vxx + vyy);
        out[2 * NPTS + g] = ux + vy;
    }
}

extern "C" void kernel_launch(void* const* d_in, const int* in_sizes, int n_in,
                              void* d_out, int out_size, void* d_ws, size_t ws_size,
                              hipStream_t stream) {
    const float* t_ = (const float*)d_in[0];
    const float* x_ = (const float*)d_in[1];
    const float* y_ = (const float*)d_in[2];
    const float* W[7];
    const float* b[7];
    for (int i = 0; i < 7; ++i) {
        W[i] = (const float*)d_in[3 + 2 * i];
        b[i] = (const float*)d_in[4 + 2 * i];
    }
    float* out = (float*)d_out;

    f16* bh  = (f16*)d_ws;               // 327680 f16
    f16* b6h = bh + 5 * 65536;           // 4096 f16

    hipLaunchKernelGGL(prep_kernel, dim3(162), dim3(256), 0, stream,
                       W[1], W[2], W[3], W[4], W[5], W[6], bh, b6h);
    hipLaunchKernelGGL(pinn_ns_mfma, dim3(NPTS / PW), dim3(256), 0, stream,
                       t_, x_, y_, W[0], b[0],
                       b[1], b[2], b[3], b[4], b[5], b[6],
                       bh, b6h, out);
}

// Round 7
// 146.620 us; speedup vs baseline: 1.6355x; 1.0341x over previous
//
#include <hip/hip_runtime.h>

#define NPTS 16384
#define PW 16
#define NU (1.0f / 100.0f)

typedef _Float16 f16;
typedef __attribute__((ext_vector_type(4))) _Float16 f16x4;
typedef __attribute__((ext_vector_type(8))) _Float16 f16x8;
typedef __attribute__((ext_vector_type(4))) float f32x4;

// granule swizzle within a 64-granule (16B each) tile: bijective, same on
// write and read; spreads writes/reads over all bank groups.
__device__ __forceinline__ int swz(int g) { return g ^ ((g >> 3) & 7); }

// ---- prep: W1..W5 (256x256) and W6 (256x3 zero-padded to 16 cols) -> MFMA
// fragment order, single f16 plane. Fragment (16x16x32): lane l holds
// M[k = kc*32 + 8*(l>>4) + j][col = nf*16 + (l&15)], j=0..7. This layout
// serves as the A-operand (A[m=col][k] = W^T) in the transposed GEMM.
__global__ __launch_bounds__(256) void prep_kernel(
    const float* __restrict__ W1, const float* __restrict__ W2,
    const float* __restrict__ W3, const float* __restrict__ W4,
    const float* __restrict__ W5, const float* __restrict__ W6,
    f16* __restrict__ bh, f16* __restrict__ b6h)
{
    int idx = blockIdx.x * 256 + threadIdx.x;
    if (idx < 40960) {
        int col = idx & 255, subk = (idx >> 8) & 3, kc = (idx >> 10) & 7, L = idx >> 13;
        const float* W = (L == 0) ? W1 : (L == 1) ? W2 : (L == 2) ? W3 : (L == 3) ? W4 : W5;
        f16x8 vh;
        #pragma unroll
        for (int j = 0; j < 8; ++j) {
            int k = kc * 32 + subk * 8 + j;
            vh[j] = (f16)W[k * 256 + col];
        }
        int nf = col >> 4, l15 = col & 15, lane = subk * 16 + l15;
        *(f16x8*)(bh + (((L * 8 + kc) * 16 + nf) * 64 + lane) * 8) = vh;
    } else {
        int u = idx - 40960;
        if (u < 512) {
            int col = u & 15, subk = (u >> 4) & 3, kc = u >> 6;
            f16x8 vh;
            #pragma unroll
            for (int j = 0; j < 8; ++j) {
                int k = kc * 32 + subk * 8 + j;
                vh[j] = (f16)((col < 3) ? W6[k * 3 + col] : 0.f);
            }
            *(f16x8*)(b6h + (kc * 64 + subk * 16 + col) * 8) = vh;
        }
    }
}

// ---- main: PW=16 points/block, 4 waves (256 thr), 3 blocks/CU.
// Transposed GEMM: Z^T[feature][point] = Wfrag(A) x State(B).
// State in LDS as B-frags: tile (c,kc) = 64 granules of 16B; granule g holds
// S[k = kc*32 + 8*(g>>4) + 0..7][point = g&15], stored at swz(g).
// Wave nq computes feature rows [nq*64, nq*64+64) for all 6 channels.
// D layout: lane l -> point = l&15, feature rows mf*16 + (l>>4)*4 + r.
// => each thread's 4 outputs per (c,mf) are 4 CONSECUTIVE features of one
// point = one b64 LDS write in next layer's B-frag layout.
__global__ __launch_bounds__(256) void pinn_ns_mfma(
    const float* __restrict__ t_, const float* __restrict__ x_, const float* __restrict__ y_,
    const float* __restrict__ W0, const float* __restrict__ b0,
    const float* __restrict__ b1, const float* __restrict__ b2,
    const float* __restrict__ b3, const float* __restrict__ b4,
    const float* __restrict__ b5, const float* __restrict__ b6,
    const f16* __restrict__ bh, const f16* __restrict__ b6h,
    float* __restrict__ out)
{
    __shared__ __align__(16) f16 afrag[6 * 8 * 512];   // 49152 B

    const int tid = threadIdx.x;
    const int lane = tid & 63;
    const int nq = tid >> 6;           // wave: feature rows nq*64 .. +63
    const int q = lane >> 4;
    const int s = lane & 15;           // point index within tile
    const int gl = swz(lane);          // B-frag read granule
    const int p0 = blockIdx.x * PW;

    // ---- layer 0: 3 -> 256 elementwise; write state B-frags.
    {
        float tv = t_[p0 + s], xv = x_[p0 + s], yv = y_[p0 + s];
        int fq0 = tid >> 4;            // 0..15
        #pragma unroll
        for (int i = 0; i < 4; ++i) {
            int fq = fq0 + 16 * i;     // feature quad 0..63 (features 4fq..4fq+3)
            int f0 = fq * 4;
            f32x4 w0 = *(const f32x4*)&W0[f0];
            f32x4 w1 = *(const f32x4*)&W0[256 + f0];
            f32x4 w2 = *(const f32x4*)&W0[512 + f0];
            f32x4 bb = *(const f32x4*)&b0[f0];
            f16x4 o[6];
            #pragma unroll
            for (int ff = 0; ff < 4; ++ff) {
                float z = tv * w0[ff] + xv * w1[ff] + yv * w2[ff] + bb[ff];
                float sv, cv;
                __sincosf(z, &sv, &cv);
                o[0][ff] = (f16)sv;
                o[1][ff] = (f16)(cv * w0[ff]);
                o[2][ff] = (f16)(cv * w1[ff]);
                o[3][ff] = (f16)(cv * w2[ff]);
                o[4][ff] = (f16)(-sv * w1[ff] * w1[ff]);
                o[5][ff] = (f16)(-sv * w2[ff] * w2[ff]);
            }
            int kc = fq >> 3;
            int g = swz(16 * ((fq >> 1) & 3) + s);
            int half = fq & 1;
            #pragma unroll
            for (int c = 0; c < 6; ++c)
                *(f16x4*)&afrag[(c * 8 + kc) * 512 + g * 8 + half * 4] = o[c];
        }
    }
    __syncthreads();

    // ---- layers 1..5
    const float* bias[5] = {b1, b2, b3, b4, b5};
    const f16x8* A = (const f16x8*)afrag;
    for (int L = 0; L < 5; ++L) {
        const f16x8* wH = (const f16x8*)bh + L * 8192;
        f32x4 acc[6][4];
        #pragma unroll
        for (int c = 0; c < 6; ++c)
            #pragma unroll
            for (int f = 0; f < 4; ++f)
                acc[c][f] = (f32x4){0.f, 0.f, 0.f, 0.f};

        f16x8 Wc[4];
        #pragma unroll
        for (int f = 0; f < 4; ++f)
            Wc[f] = wH[(nq * 4 + f) * 64 + lane];

        #pragma unroll
        for (int kc = 0; kc < 8; ++kc) {
            f16x8 Wn[4];
            if (kc < 7) {
                #pragma unroll
                for (int f = 0; f < 4; ++f)
                    Wn[f] = wH[((kc + 1) * 16 + nq * 4 + f) * 64 + lane];
            }
            f16x8 S[6];
            #pragma unroll
            for (int c = 0; c < 6; ++c)
                S[c] = A[(c * 8 + kc) * 64 + gl];
            #pragma unroll
            for (int c = 0; c < 6; ++c)
                #pragma unroll
                for (int f = 0; f < 4; ++f)
                    acc[c][f] = __builtin_amdgcn_mfma_f32_16x16x32_f16(Wc[f], S[c], acc[c][f], 0, 0, 0);
            if (kc < 7) {
                #pragma unroll
                for (int f = 0; f < 4; ++f)
                    Wc[f] = Wn[f];
            }
        }
        __syncthreads();  // all B-frag reads done before overwrite

        const float* bbp = bias[L];
        #pragma unroll
        for (int mf = 0; mf < 4; ++mf) {
            int fbase = nq * 64 + mf * 16 + 4 * q;   // 4 consecutive features
            f32x4 bq = *(const f32x4*)&bbp[fbase];
            f16x4 o[6];
            #pragma unroll
            for (int r = 0; r < 4; ++r) {
                float z = acc[0][mf][r] + bq[r];
                float zt = acc[1][mf][r], zx = acc[2][mf][r], zy = acc[3][mf][r];
                float zxx = acc[4][mf][r], zyy = acc[5][mf][r];
                float sv, cv;
                __sincosf(z, &sv, &cv);
                o[0][r] = (f16)sv;
                o[1][r] = (f16)(cv * zt);
                o[2][r] = (f16)(cv * zx);
                o[3][r] = (f16)(cv * zy);
                o[4][r] = (f16)(cv * zxx - sv * zx * zx);
                o[5][r] = (f16)(cv * zyy - sv * zy * zy);
            }
            int kc = 2 * nq + (mf >> 1);
            int g = swz(16 * (2 * (mf & 1) + (q >> 1)) + s);
            int half = q & 1;
            #pragma unroll
            for (int c = 0; c < 6; ++c)
                *(f16x4*)&afrag[(c * 8 + kc) * 512 + g * 8 + half * 4] = o[c];
        }
        __syncthreads();
    }

    // ---- layer 6: 256 -> 3 (cols 3..15 zero). Wave 0 computes all channels;
    // lanes q==0 hold (u,v,p) of point s in rows r=0..2 -> residuals in-lane.
    if (nq == 0) {
        f32x4 a6[6];
        #pragma unroll
        for (int c = 0; c < 6; ++c)
            a6[c] = (f32x4){0.f, 0.f, 0.f, 0.f};
        const f16x8* w6 = (const f16x8*)b6h;
        #pragma unroll
        for (int kc = 0; kc < 8; ++kc) {
            f16x8 Wf = w6[kc * 64 + lane];
            #pragma unroll
            for (int c = 0; c < 6; ++c)
                a6[c] = __builtin_amdgcn_mfma_f32_16x16x32_f16(Wf, A[(c * 8 + kc) * 64 + gl], a6[c], 0, 0, 0);
        }
        if (lane < 16) {
            int g = p0 + s;
            float u_  = a6[0][0] + b6[0], v_ = a6[0][1] + b6[1];
            float ut  = a6[1][0], vt  = a6[1][1];
            float ux  = a6[2][0], vx  = a6[2][1], px = a6[2][2];
            float uy  = a6[3][0], vy  = a6[3][1], py = a6[3][2];
            float uxx = a6[4][0], vxx = a6[4][1];
            float uyy = a6[5][0], vyy = a6[5][1];
            out[g]            = ut + (u_ * ux + v_ * uy) + px - NU * (uxx + uyy);
            out[NPTS + g]     = vt + (u_ * vx + v_ * vy) + py - NU * (vxx + vyy);
            out[2 * NPTS + g] = ux + vy;
        }
    }
}

extern "C" void kernel_launch(void* const* d_in, const int* in_sizes, int n_in,
                              void* d_out, int out_size, void* d_ws, size_t ws_size,
                              hipStream_t stream) {
    const float* t_ = (const float*)d_in[0];
    const float* x_ = (const float*)d_in[1];
    const float* y_ = (const float*)d_in[2];
    const float* W[7];
    const float* b[7];
    for (int i = 0; i < 7; ++i) {
        W[i] = (const float*)d_in[3 + 2 * i];
        b[i] = (const float*)d_in[4 + 2 * i];
    }
    float* out = (float*)d_out;

    f16* bh  = (f16*)d_ws;               // 327680 f16
    f16* b6h = bh + 5 * 65536;           // 4096 f16

    hipLaunchKernelGGL(prep_kernel, dim3(162), dim3(256), 0, stream,
                       W[1], W[2], W[3], W[4], W[5], W[6], bh, b6h);
    hipLaunchKernelGGL(pinn_ns_mfma, dim3(NPTS / PW), dim3(256), 0, stream,
                       t_, x_, y_, W[0], b[0],
                       b[1], b[2], b[3], b[4], b[5], b[6],
                       bh, b6h, out);
}

// Round 8
// 143.845 us; speedup vs baseline: 1.6670x; 1.0193x over previous
//
#include <hip/hip_runtime.h>

#define NPTS 16384
#define PW 16
#define NCH 5
#define NU (1.0f / 100.0f)

typedef _Float16 f16;
typedef __attribute__((ext_vector_type(4))) _Float16 f16x4;
typedef __attribute__((ext_vector_type(8))) _Float16 f16x8;
typedef __attribute__((ext_vector_type(4))) float f32x4;

// granule swizzle within a 64-granule (16B each) tile: bijective, same on
// write and read; spreads writes/reads over all bank groups.
__device__ __forceinline__ int swz(int g) { return g ^ ((g >> 3) & 7); }

// ---- prep: W1..W5 (256x256) and W6 (256x3 zero-padded to 16 cols) -> MFMA
// fragment order, single f16 plane. Fragment (16x16x32): lane l holds
// M[k = kc*32 + 8*(l>>4) + j][col = nf*16 + (l&15)], j=0..7. Serves as the
// A-operand (A[m=col][k] = W^T) in the transposed GEMM.
__global__ __launch_bounds__(256) void prep_kernel(
    const float* __restrict__ W1, const float* __restrict__ W2,
    const float* __restrict__ W3, const float* __restrict__ W4,
    const float* __restrict__ W5, const float* __restrict__ W6,
    f16* __restrict__ bh, f16* __restrict__ b6h)
{
    int idx = blockIdx.x * 256 + threadIdx.x;
    if (idx < 40960) {
        int col = idx & 255, subk = (idx >> 8) & 3, kc = (idx >> 10) & 7, L = idx >> 13;
        const float* W = (L == 0) ? W1 : (L == 1) ? W2 : (L == 2) ? W3 : (L == 3) ? W4 : W5;
        f16x8 vh;
        #pragma unroll
        for (int j = 0; j < 8; ++j) {
            int k = kc * 32 + subk * 8 + j;
            vh[j] = (f16)W[k * 256 + col];
        }
        int nf = col >> 4, l15 = col & 15, lane = subk * 16 + l15;
        *(f16x8*)(bh + (((L * 8 + kc) * 16 + nf) * 64 + lane) * 8) = vh;
    } else {
        int u = idx - 40960;
        if (u < 512) {
            int col = u & 15, subk = (u >> 4) & 3, kc = u >> 6;
            f16x8 vh;
            #pragma unroll
            for (int j = 0; j < 8; ++j) {
                int k = kc * 32 + subk * 8 + j;
                vh[j] = (f16)((col < 3) ? W6[k * 3 + col] : 0.f);
            }
            *(f16x8*)(b6h + (kc * 64 + subk * 16 + col) * 8) = vh;
        }
    }
}

// ---- main: PW=16 points/block, 4 waves, 5 channels (0=val,1=dt,2=dx,3=dy,
// 4=spatial Laplacian). LDS = 40960 B -> 4 blocks/CU exactly; the whole
// 1024-block grid is co-resident (zero tail).
// Transposed GEMM: Z^T[feature][point] = Wfrag(A) x State(B).
// State B-frags: tile (c,kc) = 64 granules of 16B; granule g holds
// S[k = kc*32 + 8*(g>>4) + 0..7][point = g&15], stored at swz(g).
// Wave nq computes feature rows [nq*64, nq*64+64) for all channels.
// D layout: lane l -> point = l&15, feature rows mf*16 + (l>>4)*4 + r
// => each thread's 4 outputs per (c,mf) are 4 consecutive features of one
// point = one b64 LDS write in next layer's B-frag layout.
__global__ __launch_bounds__(256) void pinn_ns_mfma(
    const float* __restrict__ t_, const float* __restrict__ x_, const float* __restrict__ y_,
    const float* __restrict__ W0, const float* __restrict__ b0,
    const float* __restrict__ b1, const float* __restrict__ b2,
    const float* __restrict__ b3, const float* __restrict__ b4,
    const float* __restrict__ b5, const float* __restrict__ b6,
    const f16* __restrict__ bh, const f16* __restrict__ b6h,
    float* __restrict__ out)
{
    __shared__ __align__(16) f16 afrag[NCH * 8 * 512];   // 40960 B

    const int tid = threadIdx.x;
    const int lane = tid & 63;
    const int nq = tid >> 6;           // wave: feature rows nq*64 .. +63
    const int q = lane >> 4;
    const int s = lane & 15;           // point index within tile
    const int gl = swz(lane);          // B-frag read granule
    const int p0 = blockIdx.x * PW;

    // ---- layer 0: 3 -> 256 elementwise; write state B-frags.
    // z = wt*t + wx*x + wy*y + b: z_x=wx, z_y=wy, z_lap=0
    // a_lap = -sin z * (wx^2 + wy^2)
    {
        float tv = t_[p0 + s], xv = x_[p0 + s], yv = y_[p0 + s];
        int fq0 = tid >> 4;            // 0..15
        #pragma unroll
        for (int i = 0; i < 4; ++i) {
            int fq = fq0 + 16 * i;     // feature quad 0..63 (features 4fq..4fq+3)
            int f0 = fq * 4;
            f32x4 w0 = *(const f32x4*)&W0[f0];
            f32x4 w1 = *(const f32x4*)&W0[256 + f0];
            f32x4 w2 = *(const f32x4*)&W0[512 + f0];
            f32x4 bb = *(const f32x4*)&b0[f0];
            f16x4 o[NCH];
            #pragma unroll
            for (int ff = 0; ff < 4; ++ff) {
                float z = tv * w0[ff] + xv * w1[ff] + yv * w2[ff] + bb[ff];
                float sv, cv;
                __sincosf(z, &sv, &cv);
                o[0][ff] = (f16)sv;
                o[1][ff] = (f16)(cv * w0[ff]);
                o[2][ff] = (f16)(cv * w1[ff]);
                o[3][ff] = (f16)(cv * w2[ff]);
                o[4][ff] = (f16)(-sv * (w1[ff] * w1[ff] + w2[ff] * w2[ff]));
            }
            int kc = fq >> 3;
            int g = swz(16 * ((fq >> 1) & 3) + s);
            int half = fq & 1;
            #pragma unroll
            for (int c = 0; c < NCH; ++c)
                *(f16x4*)&afrag[(c * 8 + kc) * 512 + g * 8 + half * 4] = o[c];
        }
    }
    __syncthreads();

    // ---- layers 1..5
    const float* bias[5] = {b1, b2, b3, b4, b5};
    const f16x8* A = (const f16x8*)afrag;
    for (int L = 0; L < 5; ++L) {
        const f16x8* wH = (const f16x8*)bh + L * 8192;
        f32x4 acc[NCH][4];
        #pragma unroll
        for (int c = 0; c < NCH; ++c)
            #pragma unroll
            for (int f = 0; f < 4; ++f)
                acc[c][f] = (f32x4){0.f, 0.f, 0.f, 0.f};

        f16x8 Wc[4];
        #pragma unroll
        for (int f = 0; f < 4; ++f)
            Wc[f] = wH[(nq * 4 + f) * 64 + lane];

        #pragma unroll
        for (int kc = 0; kc < 8; ++kc) {
            f16x8 Wn[4];
            if (kc < 7) {
                #pragma unroll
                for (int f = 0; f < 4; ++f)
                    Wn[f] = wH[((kc + 1) * 16 + nq * 4 + f) * 64 + lane];
            }
            f16x8 S[NCH];
            #pragma unroll
            for (int c = 0; c < NCH; ++c)
                S[c] = A[(c * 8 + kc) * 64 + gl];
            #pragma unroll
            for (int c = 0; c < NCH; ++c)
                #pragma unroll
                for (int f = 0; f < 4; ++f)
                    acc[c][f] = __builtin_amdgcn_mfma_f32_16x16x32_f16(Wc[f], S[c], acc[c][f], 0, 0, 0);
            if (kc < 7) {
                #pragma unroll
                for (int f = 0; f < 4; ++f)
                    Wc[f] = Wn[f];
            }
        }
        __syncthreads();  // all B-frag reads done before overwrite

        const float* bbp = bias[L];
        #pragma unroll
        for (int mf = 0; mf < 4; ++mf) {
            int fbase = nq * 64 + mf * 16 + 4 * q;   // 4 consecutive features
            f32x4 bq = *(const f32x4*)&bbp[fbase];
            f16x4 o[NCH];
            #pragma unroll
            for (int r = 0; r < 4; ++r) {
                float z = acc[0][mf][r] + bq[r];
                float zt = acc[1][mf][r], zx = acc[2][mf][r], zy = acc[3][mf][r];
                float zlap = acc[4][mf][r];
                float sv, cv;
                __sincosf(z, &sv, &cv);
                o[0][r] = (f16)sv;
                o[1][r] = (f16)(cv * zt);
                o[2][r] = (f16)(cv * zx);
                o[3][r] = (f16)(cv * zy);
                o[4][r] = (f16)(cv * zlap - sv * (zx * zx + zy * zy));
            }
            int kc = 2 * nq + (mf >> 1);
            int g = swz(16 * (2 * (mf & 1) + (q >> 1)) + s);
            int half = q & 1;
            #pragma unroll
            for (int c = 0; c < NCH; ++c)
                *(f16x4*)&afrag[(c * 8 + kc) * 512 + g * 8 + half * 4] = o[c];
        }
        __syncthreads();
    }

    // ---- layer 6: 256 -> 3 (cols 3..15 zero). Wave 0 computes all channels;
    // lanes q==0 hold (u,v,p) of point s in rows r=0..2 -> residuals in-lane.
    if (nq == 0) {
        f32x4 a6[NCH];
        #pragma unroll
        for (int c = 0; c < NCH; ++c)
            a6[c] = (f32x4){0.f, 0.f, 0.f, 0.f};
        const f16x8* w6 = (const f16x8*)b6h;
        #pragma unroll
        for (int kc = 0; kc < 8; ++kc) {
            f16x8 Wf = w6[kc * 64 + lane];
            #pragma unroll
            for (int c = 0; c < NCH; ++c)
                a6[c] = __builtin_amdgcn_mfma_f32_16x16x32_f16(Wf, A[(c * 8 + kc) * 64 + gl], a6[c], 0, 0, 0);
        }
        if (lane < 16) {
            int g = p0 + s;
            float u_   = a6[0][0] + b6[0], v_ = a6[0][1] + b6[1];
            float ut   = a6[1][0], vt   = a6[1][1];
            float ux   = a6[2][0], vx   = a6[2][1], px = a6[2][2];
            float uy   = a6[3][0], vy   = a6[3][1], py = a6[3][2];
            float ulap = a6[4][0], vlap = a6[4][1];
            out[g]            = ut + (u_ * ux + v_ * uy) + px - NU * ulap;
            out[NPTS + g]     = vt + (u_ * vx + v_ * vy) + py - NU * vlap;
            out[2 * NPTS + g] = ux + vy;
        }
    }
}

extern "C" void kernel_launch(void* const* d_in, const int* in_sizes, int n_in,
                              void* d_out, int out_size, void* d_ws, size_t ws_size,
                              hipStream_t stream) {
    const float* t_ = (const float*)d_in[0];
    const float* x_ = (const float*)d_in[1];
    const float* y_ = (const float*)d_in[2];
    const float* W[7];
    const float* b[7];
    for (int i = 0; i < 7; ++i) {
        W[i] = (const float*)d_in[3 + 2 * i];
        b[i] = (const float*)d_in[4 + 2 * i];
    }
    float* out = (float*)d_out;

    f16* bh  = (f16*)d_ws;               // 327680 f16
    f16* b6h = bh + 5 * 65536;           // 4096 f16

    hipLaunchKernelGGL(prep_kernel, dim3(162), dim3(256), 0, stream,
                       W[1], W[2], W[3], W[4], W[5], W[6], bh, b6h);
    hipLaunchKernelGGL(pinn_ns_mfma, dim3(NPTS / PW), dim3(256), 0, stream,
                       t_, x_, y_, W[0], b[0],
                       b[1], b[2], b[3], b[4], b[5], b[6],
                       bh, b6h, out);
}